// Round 7
// baseline (183.258 us; speedup 1.0000x reference)
//
#include <hip/hip_runtime.h>

#define MAX_A 64
#define REP 16   // SLOPE-MEASUREMENT ROUND: repeat compute 16x inside the
                 // kernel (idempotent). Marginal reps carry no launch
                 // overhead -> slope isolates true compute time, and the
                 // kernel becomes the longest dispatch -> visible counters.

// Divisionless exact threshold (see R6): RN(inter/uni) >= 0.7f
//   <=> signbit(uni) ? inter < m*uni : inter > m*uni,  m = 0x1.666665p-1,
// all operations exact in f64.
#define IOU_M 0x1.666665p-1

__global__ __launch_bounds__(256) void assign_cls_b8(
    const float4* __restrict__ bbox,      // [B, N]
    const float4* __restrict__ gt,        // [B, A]
    const int*    __restrict__ gt_counts, // [B]
    const int*    __restrict__ counts,    // [B]
    int*          __restrict__ out,       // [B, N]
    int N, int A, int nwMask)             // nwMask = N/64 - 1 (pow2)
{
    const int lane = threadIdx.x & 63;
    const int w    = threadIdx.x >> 6;
    const int half = blockIdx.x & 1;
    const int b    = half * 4 + w;
    const int q    = blockIdx.x >> 1;
    const int nw   = (q * 421) & nwMask;
    const int n    = nw * 64 + lane;

    __shared__ float4 sgt[4][MAX_A];
    __shared__ float  sga[4][MAX_A];
    for (int i = threadIdx.x; i < 4 * A; i += 256) {
        const int lb = i / A, a = i - lb * A;
        float4 g = gt[(size_t)(half * 4 + lb) * A + a];
        sgt[lb][a] = g;
        sga[lb][a] = (g.z - g.x) * (g.w - g.y);
    }
    __syncthreads();

    const int cnt = counts[b];
    const int G   = min(gt_counts[b], A);

    int label = 0;
    if (n < cnt) {
        float4 bb = bbox[(size_t)b * N + n];

        #pragma unroll 1
        for (int rep = 0; rep < REP; ++rep) {
            // Defeat CSE across reps: compiler must treat bb as fresh.
            asm volatile("" : "+v"(bb.x), "+v"(bb.y), "+v"(bb.z), "+v"(bb.w));
            const float area = (bb.z - bb.x) * (bb.w - bb.y);
            int l = 0;
            #pragma unroll 4
            for (int g = 0; g < G; ++g) {
                const float4 gb = sgt[w][g];
                const float yy1 = fminf(fmaxf(bb.x, gb.x), gb.z);
                const float xx1 = fminf(fmaxf(bb.y, gb.y), gb.w);
                const float yy2 = fminf(fmaxf(bb.z, gb.x), gb.z);
                const float xx2 = fminf(fmaxf(bb.w, gb.y), gb.w);
                const float inter = (yy2 - yy1) * (xx2 - xx1);
                const float uni   = (area + sga[w][g]) - inter;
                const double mu = IOU_M * (double)uni;
                const double di = (double)inter;
                l |= (__float_as_int(uni) < 0) ? (di < mu) : (di > mu);
            }
            label |= l;   // idempotent: every rep computes the same l
        }
    }
    out[(size_t)b * N + n] = label;
}

// Generic fallback (any B/A/N) — single pass, correct, not perf-relevant.
__global__ __launch_bounds__(256) void assign_cls_generic(
    const float4* __restrict__ bbox, const float4* __restrict__ gt,
    const int* __restrict__ gt_counts, const int* __restrict__ counts,
    int* __restrict__ out, int N, int A)
{
    const int b = blockIdx.y;
    const int n = blockIdx.x * blockDim.x + threadIdx.x;
    if (n >= N) return;
    const int cnt = counts[b];
    const int G   = min(gt_counts[b], A);
    int label = 0;
    if (n < cnt) {
        const float4 bb = bbox[(size_t)b * N + n];
        const float area = (bb.z - bb.x) * (bb.w - bb.y);
        for (int g = 0; g < G; ++g) {
            const float4 gb = gt[(size_t)b * A + g];
            const float ga = (gb.z - gb.x) * (gb.w - gb.y);
            const float yy1 = fminf(fmaxf(bb.x, gb.x), gb.z);
            const float xx1 = fminf(fmaxf(bb.y, gb.y), gb.w);
            const float yy2 = fminf(fmaxf(bb.z, gb.x), gb.z);
            const float xx2 = fminf(fmaxf(bb.w, gb.y), gb.w);
            const float inter = (yy2 - yy1) * (xx2 - xx1);
            const float uni   = (area + ga) - inter;
            const double mu = IOU_M * (double)uni;
            const double di = (double)inter;
            label |= (__float_as_int(uni) < 0) ? (di < mu) : (di > mu);
        }
    }
    out[(size_t)b * N + n] = label;
}

extern "C" void kernel_launch(void* const* d_in, const int* in_sizes, int n_in,
                              void* d_out, int out_size, void* d_ws, size_t ws_size,
                              hipStream_t stream) {
    const float4* bbox      = (const float4*)d_in[0];
    const float4* gt        = (const float4*)d_in[1];
    const int*    gt_counts = (const int*)d_in[2];
    const int*    counts    = (const int*)d_in[3];
    int*          out       = (int*)d_out;

    const int B = in_sizes[2];
    const int A = in_sizes[1] / (4 * B);
    const int N = in_sizes[0] / (4 * B);

    const int nwPerBatch = N / 64;
    const bool pow2 = (nwPerBatch & (nwPerBatch - 1)) == 0;
    if (B == 8 && A <= MAX_A && (N % 64) == 0 && pow2) {
        dim3 block(256, 1, 1);
        dim3 grid(2 * nwPerBatch, 1, 1);
        assign_cls_b8<<<grid, block, 0, stream>>>(bbox, gt, gt_counts, counts,
                                                  out, N, A, nwPerBatch - 1);
    } else {
        dim3 block(256, 1, 1);
        dim3 grid((N + 255) / 256, B, 1);
        assign_cls_generic<<<grid, block, 0, stream>>>(bbox, gt, gt_counts,
                                                       counts, out, N, A);
    }
}

// Round 8
// 9.505 us; speedup vs baseline: 19.2793x; 19.2793x over previous
//
#include <hip/hip_runtime.h>

#define MAX_A 64

// m = 0x1.666665p-1 = midpoint(pred(0.7f), 0.7f). pred has even mantissa =>
// RN(i/u) >= 0.7f  <=>  real i/u > m  <=>  sign-aware compare of i vs m*u.
// t = fma64(m, u, -i) has sign(t) == sign(m*u - i) EXACTLY (m*u needs 49
// bits -> exact in f64; RN preserves sign; t==0 iff i==m*u -> predicate
// false either way). All +-0 / inf / NaN quotient cases verified.
#define IOU_M64 0x1.666665p-1

// Specialized B==8, A==64, N%64==0 kernel.
// - Wave W -> batch b=W&7 (wave w of block covers batch half*4+w), chunk
//   scrambled for CU load balance.
// - Each wave COMPACTS its batch's gt list at staging: gt with gy1>gy2 or
//   gx1>gx2 are provably always-false (clip pins a coord pair -> inter=+-0
//   -> quotient in {+-0, NaN} < 0.7) and are dropped. Random-uniform gt
//   are ~75% inverted => ~4x fewer inner iterations.
// - Post-compaction gt are well-ordered => clip == v_med3_f32 (exact).
__global__ __launch_bounds__(256) void assign_cls_b8(
    const float4* __restrict__ bbox,      // [B, N]
    const float4* __restrict__ gt,        // [B, A]
    const int*    __restrict__ gt_counts, // [B]
    const int*    __restrict__ counts,    // [B]
    int*          __restrict__ out,       // [B, N]
    int N, int A, int nwMask)             // nwMask = N/64 - 1 (pow2)
{
    const int lane = threadIdx.x & 63;
    const int w    = threadIdx.x >> 6;          // wave in block: 0..3
    const int half = blockIdx.x & 1;
    const int b    = half * 4 + w;              // this wave's batch
    const int q    = blockIdx.x >> 1;
    const int nw   = (q * 421) & nwMask;        // bijective scramble
    const int n    = nw * 64 + lane;

    __shared__ float4 sgt[4][MAX_A];
    __shared__ float  sga[4][MAX_A];

    // --- wave-local gt staging with compaction (A==64 == wave size) ---
    const int G = min(gt_counts[b], A);
    const float4 g = gt[(size_t)b * A + lane];          // lane a reads gt[a]
    const bool valid = (lane < G) & (g.x <= g.z) & (g.y <= g.w);
    const unsigned long long mask = __ballot(valid);
    const int pos = __popcll(mask & ((1ULL << lane) - 1ULL));
    if (valid) {
        sgt[w][pos] = g;
        sga[w][pos] = (g.z - g.x) * (g.w - g.y);        // ga (>= 0 here)
    }
    const int Gp = __popcll(mask);                       // compacted count
    __syncthreads();   // also orders LDS writes->reads; all waves reach it

    const int cnt = counts[b];                           // wave-uniform
    int label = 0;
    if (n < cnt) {
        const float4 bb = bbox[(size_t)b * N + n];       // coalesced dwordx4
        const float area = (bb.z - bb.x) * (bb.w - bb.y);

        #pragma unroll 4
        for (int i = 0; i < Gp; ++i) {
            const float4 gb = sgt[w][i];                 // uniform: broadcast
            const float yy1 = __builtin_amdgcn_fmed3f(bb.x, gb.x, gb.z);
            const float xx1 = __builtin_amdgcn_fmed3f(bb.y, gb.y, gb.w);
            const float yy2 = __builtin_amdgcn_fmed3f(bb.z, gb.x, gb.z);
            const float xx2 = __builtin_amdgcn_fmed3f(bb.w, gb.y, gb.w);
            const float inter = (yy2 - yy1) * (xx2 - xx1);
            const float uni   = (area + sga[w][i]) - inter;
            const double t = fma(IOU_M64, (double)uni, -(double)inter);
            label |= (__float_as_int(uni) < 0) ? (t > 0.0) : (t < 0.0);
        }
    }
    out[(size_t)b * N + n] = label;
}

// Generic fallback (any B/A/N): no compaction/med3 assumptions, exact
// min/max clip + divisionless fma sign test.
__global__ __launch_bounds__(256) void assign_cls_generic(
    const float4* __restrict__ bbox, const float4* __restrict__ gt,
    const int* __restrict__ gt_counts, const int* __restrict__ counts,
    int* __restrict__ out, int N, int A)
{
    const int b = blockIdx.y;
    const int n = blockIdx.x * blockDim.x + threadIdx.x;
    if (n >= N) return;
    const int cnt = counts[b];
    const int G   = min(gt_counts[b], A);
    int label = 0;
    if (n < cnt) {
        const float4 bb = bbox[(size_t)b * N + n];
        const float area = (bb.z - bb.x) * (bb.w - bb.y);
        for (int g = 0; g < G; ++g) {
            const float4 gb = gt[(size_t)b * A + g];
            const float ga = (gb.z - gb.x) * (gb.w - gb.y);
            const float yy1 = fminf(fmaxf(bb.x, gb.x), gb.z);
            const float xx1 = fminf(fmaxf(bb.y, gb.y), gb.w);
            const float yy2 = fminf(fmaxf(bb.z, gb.x), gb.z);
            const float xx2 = fminf(fmaxf(bb.w, gb.y), gb.w);
            const float inter = (yy2 - yy1) * (xx2 - xx1);
            const float uni   = (area + ga) - inter;
            const double t = fma(IOU_M64, (double)uni, -(double)inter);
            label |= (__float_as_int(uni) < 0) ? (t > 0.0) : (t < 0.0);
        }
    }
    out[(size_t)b * N + n] = label;
}

extern "C" void kernel_launch(void* const* d_in, const int* in_sizes, int n_in,
                              void* d_out, int out_size, void* d_ws, size_t ws_size,
                              hipStream_t stream) {
    const float4* bbox      = (const float4*)d_in[0];
    const float4* gt        = (const float4*)d_in[1];
    const int*    gt_counts = (const int*)d_in[2];
    const int*    counts    = (const int*)d_in[3];
    int*          out       = (int*)d_out;

    const int B = in_sizes[2];
    const int A = in_sizes[1] / (4 * B);
    const int N = in_sizes[0] / (4 * B);

    const int nwPerBatch = N / 64;
    const bool pow2 = (nwPerBatch & (nwPerBatch - 1)) == 0;
    if (B == 8 && A == 64 && (N % 64) == 0 && pow2) {
        dim3 block(256, 1, 1);
        dim3 grid(2 * nwPerBatch, 1, 1);     // 2048 blocks, 4 waves each
        assign_cls_b8<<<grid, block, 0, stream>>>(bbox, gt, gt_counts, counts,
                                                  out, N, A, nwPerBatch - 1);
    } else {
        dim3 block(256, 1, 1);
        dim3 grid((N + 255) / 256, B, 1);
        assign_cls_generic<<<grid, block, 0, stream>>>(bbox, gt, gt_counts,
                                                       counts, out, N, A);
    }
}